// Round 17
// baseline (193.038 us; speedup 1.0000x reference)
//
#include <hip/hip_runtime.h>
#include <hip/hip_fp16.h>

#define NEG 0.2f
#define RW 512      // nodes per region
#define RSH 9       // log2(RW)
#define RCAP 18432  // region edge capacity: mean 16384, sigma ~127 -> +16 sigma

typedef _Float16 f16x8 __attribute__((ext_vector_type(8)));
typedef float f32x4 __attribute__((ext_vector_type(4)));

__device__ __forceinline__ unsigned int pack2(float lo, float hi) {
    union { __half2 h; unsigned int u; } cv;
    cv.h = __floats2half2_rn(lo, hi);
    return cv.u;
}

// ---------------- k_prep: W[K][M] fp32 -> Wt[M][K] fp16 (LDS 64x64 tile transpose) ----------------

__global__ __launch_bounds__(256) void k_prep(const float* __restrict__ W1,
                                              const float* __restrict__ W2,
                                              __half* __restrict__ Wt1, __half* __restrict__ Wt2) {
    __shared__ float tile[64][65];
    int b = blockIdx.x;  // 0..5: 4 tiles of W1 (128x128), 2 tiles of W2 (128x64)
    const float* W;
    __half* Wt;
    int Mw, kt, mt;
    if (b < 4) { W = W1; Wt = Wt1; Mw = 128; kt = b >> 1; mt = b & 1; }
    else       { W = W2; Wt = Wt2; Mw = 64;  kt = b - 4;  mt = 0; }
    int tid = threadIdx.x;
    for (int i = tid; i < 4096; i += 256) {
        int kr = i >> 6, mc = i & 63;
        tile[kr][mc] = W[(size_t)(kt * 64 + kr) * Mw + mt * 64 + mc];
    }
    __syncthreads();
    for (int i = tid; i < 512; i += 256) {
        int m = i >> 3, c8 = i & 7;
        __half tmp[8];
#pragma unroll
        for (int j = 0; j < 8; j++) tmp[j] = (__half)tile[c8 * 8 + j][m];
        *reinterpret_cast<uint4*>(&Wt[(size_t)(mt * 64 + m) * 128 + kt * 64 + c8 * 8]) =
            *reinterpret_cast<uint4*>(tmp);
    }
}

// ---------------- MFMA GEMM + fused scores (+ co-scheduled partition) ----------------
// Yh[n,M] (fp16) = X[n,K] @ W[K,M] via v_mfma_f32_16x16x32_f16, fp32 accum.
// A/B frags loaded straight from global (X coalesced 128B-granule; Wt L1/L2-hot);
// no staging LDS, ONE barrier (epilogue LDS tile for coalesced stores + scores).
// A: row=lane&15, k=(lane>>4)*8+e ; B: col=lane&15, same k ; D: col=lane&15,
// row=(lane>>4)*4+reg (guide-verified). PART: odd blocks run the edge partition.

template <int K, int M, int H, bool PART, bool XHALF>
__global__ __launch_bounds__(256) void k_gemm(const void* __restrict__ Xv,
                                              const __half* __restrict__ Wt,
                                              const float* __restrict__ a_src,
                                              const float* __restrict__ a_dst,
                                              __half* __restrict__ Yh,
                                              float* __restrict__ asrc,
                                              float* __restrict__ adst, int n,
                                              const int* __restrict__ esrc,
                                              const int* __restrict__ edst, int E,
                                              int NRg, int gemmCount, int partCount,
                                              int* rcur, unsigned int* part) {
    constexpr int NT = M / 32;  // col-tiles per wave (M=128 -> 4, M=64 -> 2)
    __shared__ __half htile[32][M + 4];
    int tid = threadIdx.x;
    int bix = PART ? (blockIdx.x >> 1) : blockIdx.x;

    if (PART && (blockIdx.x & 1)) {
        // ---------- partition-only block ----------
        if (bix >= partCount) return;
        __shared__ int ph[128];
        __shared__ int pb[128];
        int i0 = (bix * 256 + tid) * 8;
        int ds[8], ss[8];
        if (i0 + 7 < E) {
            int4 a = *reinterpret_cast<const int4*>(&edst[i0]);
            int4 b = *reinterpret_cast<const int4*>(&edst[i0 + 4]);
            ds[0] = a.x; ds[1] = a.y; ds[2] = a.z; ds[3] = a.w;
            ds[4] = b.x; ds[5] = b.y; ds[6] = b.z; ds[7] = b.w;
            int4 c = *reinterpret_cast<const int4*>(&esrc[i0]);
            int4 d = *reinterpret_cast<const int4*>(&esrc[i0 + 4]);
            ss[0] = c.x; ss[1] = c.y; ss[2] = c.z; ss[3] = c.w;
            ss[4] = d.x; ss[5] = d.y; ss[6] = d.z; ss[7] = d.w;
        } else {
#pragma unroll
            for (int j = 0; j < 8; j++) {
                ds[j] = (i0 + j < E) ? edst[i0 + j] : 0;
                ss[j] = (i0 + j < E) ? esrc[i0 + j] : 0;
            }
        }
        if (tid < NRg) ph[tid] = 0;
        __syncthreads();
#pragma unroll
        for (int j = 0; j < 8; j++)
            if (i0 + j < E) atomicAdd(&ph[ds[j] >> RSH], 1);
        __syncthreads();
        if (tid < NRg) {
            int c = ph[tid];
            pb[tid] = c ? atomicAdd(&rcur[tid], c) : 0;  // coarse reserve
            ph[tid] = 0;
        }
        __syncthreads();
#pragma unroll
        for (int j = 0; j < 8; j++) {
            if (i0 + j < E) {
                int r = ds[j] >> RSH;
                int rk = atomicAdd(&ph[r], 1) + pb[r];
                if (rk < RCAP)
                    part[(size_t)r * RCAP + rk] =
                        ((unsigned int)(ds[j] & (RW - 1)) << 16) | (unsigned int)(ss[j] & 0xFFFF);
            }
        }
        return;
    }
    if (PART && bix >= gemmCount) return;
    int row0 = bix * 32;

    int w4 = tid >> 6, lane = tid & 63;
    int rt = w4 & 1;
    int ct0 = (w4 >> 1) * NT;
    int lrow = lane & 15, lk = lane >> 4;
    int grow = row0 + rt * 16 + lrow;

    f32x4 acc[NT];
#pragma unroll
    for (int i = 0; i < NT; i++) acc[i] = (f32x4){0.f, 0.f, 0.f, 0.f};

#pragma unroll 1
    for (int s = 0; s < K / 32; s++) {
        int kbase = s * 32 + lk * 8;
        f16x8 af;
        if (XHALF) {
            const __half* Xh = (const __half*)Xv;
            union { uint4 u; f16x8 v; } cv;
            cv.u = make_uint4(0u, 0u, 0u, 0u);
            if (grow < n) cv.u = *reinterpret_cast<const uint4*>(&Xh[(size_t)grow * K + kbase]);
            af = cv.v;
        } else {
            const float* X = (const float*)Xv;
            if (grow < n) {
                float4 a = *reinterpret_cast<const float4*>(&X[(size_t)grow * K + kbase]);
                float4 b = *reinterpret_cast<const float4*>(&X[(size_t)grow * K + kbase + 4]);
                af[0] = (_Float16)a.x; af[1] = (_Float16)a.y;
                af[2] = (_Float16)a.z; af[3] = (_Float16)a.w;
                af[4] = (_Float16)b.x; af[5] = (_Float16)b.y;
                af[6] = (_Float16)b.z; af[7] = (_Float16)b.w;
            } else {
#pragma unroll
                for (int j = 0; j < 8; j++) af[j] = (_Float16)0.f;
            }
        }
#pragma unroll
        for (int i = 0; i < NT; i++) {
            int col = (ct0 + i) * 16 + lrow;
            union { uint4 u; f16x8 v; } bc;
            bc.u = *reinterpret_cast<const uint4*>(&Wt[(size_t)col * K + kbase]);
            acc[i] = __builtin_amdgcn_mfma_f32_16x16x32_f16(af, bc.v, acc[i], 0, 0, 0);
        }
    }

    // D -> LDS tile (col=lane&15, row=(lane>>4)*4+j)
#pragma unroll
    for (int i = 0; i < NT; i++) {
        int col = (ct0 + i) * 16 + lrow;
#pragma unroll
        for (int j = 0; j < 4; j++) {
            int rl = rt * 16 + lk * 4 + j;
            htile[rl][col] = (__half)acc[i][j];
        }
    }
    __syncthreads();

    // coalesced fp16 store
    for (int idx = tid; idx < 32 * (M / 8); idx += 256) {
        int r = idx / (M / 8), c8 = idx % (M / 8);
        int gr = row0 + r;
        if (gr < n)
            *reinterpret_cast<uint4*>(&Yh[(size_t)gr * M + c8 * 8]) =
                *reinterpret_cast<const uint4*>(&htile[r][c8 * 8]);
    }

    // fused scores from LDS tile
    if (H == 2) {
        int row = tid >> 3, part = tid & 7;
        int gr = row0 + row;
        float s = 0.f, d = 0.f;
#pragma unroll
        for (int j = 0; j < 16; j++) {
            float hv = (float)htile[row][part * 16 + j];
            s += hv * a_src[part * 16 + j];
            d += hv * a_dst[part * 16 + j];
        }
        s += __shfl_xor(s, 1, 64); d += __shfl_xor(d, 1, 64);
        s += __shfl_xor(s, 2, 64); d += __shfl_xor(d, 2, 64);
        if (gr < n && (part & 3) == 0) {
            asrc[gr * 2 + (part >> 2)] = s;
            adst[gr * 2 + (part >> 2)] = d;
        }
    } else {
        if (tid < 128) {
            int row = tid >> 2, part = tid & 3;
            int gr = row0 + row;
            float s = 0.f, d = 0.f;
#pragma unroll
            for (int j = 0; j < 16; j++) {
                float hv = (float)htile[row][part * 16 + j];
                s += hv * a_src[part * 16 + j];
                d += hv * a_dst[part * 16 + j];
            }
            s += __shfl_xor(s, 1, 64); d += __shfl_xor(d, 1, 64);
            s += __shfl_xor(s, 2, 64); d += __shfl_xor(d, 2, 64);
            if (gr < n && part == 0) {
                asrc[gr] = s;
                adst[gr] = d;
            }
        }
    }
}

// ---------------- k_build: per-region count(LDS) + scan(LDS) -> rowptr + compact csr ----------------

__global__ __launch_bounds__(512) void k_build(const unsigned int* __restrict__ part,
                                               const int* __restrict__ rcur, int n,
                                               unsigned short* __restrict__ csr,
                                               int* __restrict__ rowptr) {
    __shared__ int hist[RW];
    __shared__ int wsum[8];
    __shared__ int rbase_s;
    int r = blockIdx.x;
    int tid = threadIdx.x, lane = tid & 63, wid = tid >> 6;
    int cnt = min(rcur[r], RCAP);
    if (tid == 0) {
        int b = 0;
        for (int j = 0; j < r; j++) b += min(rcur[j], RCAP);
        rbase_s = b;
    }
    hist[tid] = 0;
    __syncthreads();
    int rbase = rbase_s;
    const unsigned int* pr = part + (size_t)r * RCAP;

    for (int i = tid; i < cnt; i += 512) atomicAdd(&hist[pr[i] >> 16], 1);
    __syncthreads();

    int v = hist[tid];
    int incl = v;
#pragma unroll
    for (int m = 1; m < 64; m <<= 1) {
        int t = __shfl_up(incl, m, 64);
        if (lane >= m) incl += t;
    }
    if (lane == 63) wsum[wid] = incl;
    __syncthreads();
    if (wid == 0) {
        int s = (lane < 8) ? wsum[lane] : 0;
#pragma unroll
        for (int m = 1; m < 8; m <<= 1) {
            int t = __shfl_up(s, m, 64);
            if (lane >= m) s += t;
        }
        if (lane < 8) wsum[lane] = s;
    }
    __syncthreads();
    int excl = (incl - v) + (wid > 0 ? wsum[wid - 1] : 0);
    __syncthreads();
    hist[tid] = excl;  // becomes running cursor
    int g = r * RW + tid;
    if (g < n) rowptr[g] = rbase + excl;
    if (r == gridDim.x - 1 && tid == 0) rowptr[n] = rbase + cnt;
    __syncthreads();

    for (int i = tid; i < cnt; i += 512) {
        unsigned int e = pr[i];
        int rk = atomicAdd(&hist[e >> 16], 1);
        csr[rbase + rk] = (unsigned short)(e & 0xFFFF);
    }
}

// ---------------- layer-1 GAT gather (both heads), fp16 in/out (R14/R16 layout) ----------------

__global__ __launch_bounds__(256) void k_gat2(const __half* __restrict__ hh,
                                              const float* __restrict__ asrc,
                                              const float* __restrict__ adst,
                                              const int* __restrict__ rowptr,
                                              const unsigned short* __restrict__ csr_src,
                                              const float* __restrict__ bias,
                                              __half* __restrict__ outh, int n) {
    int node = blockIdx.x * 4 + (threadIdx.x >> 6);
    int lane = threadIdx.x & 63;
    if (node >= n) return;

    int beg = rowptr[node], end = rowptr[node + 1];
    float2 adn = *reinterpret_cast<const float2*>(&adst[node * 2]);
    float2 asn = *reinterpret_cast<const float2*>(&asrc[node * 2]);
    float e0 = asn.x + adn.x;
    e0 = e0 > 0.f ? e0 : NEG * e0;
    float e1 = asn.y + adn.y;
    e1 = e1 > 0.f ? e1 : NEG * e1;
    float pself0 = __expf(e0), pself1 = __expf(e1);

    int g = lane >> 4;   // edge group 0..3
    int lc = lane & 15;  // channel octet
    bool head1 = lc >= 8;

    float4 sraw = *reinterpret_cast<const float4*>(&hh[(size_t)node * 128 + lc * 8]);

    float2 acc[4];
#pragma unroll
    for (int k = 0; k < 4; k++) acc[k] = make_float2(0.f, 0.f);
    float psum0 = 0.f, psum1 = 0.f;

    for (int base = beg; base < end; base += 64) {
        int i = base + lane;
        int cnt = min(64, end - base);
        float p0 = 0.f, p1 = 0.f;
        int s = 0;
        if (i < end) {
            s = (int)csr_src[i];
            float2 a2 = *reinterpret_cast<const float2*>(&asrc[s * 2]);
            float f0 = a2.x + adn.x;
            f0 = f0 > 0.f ? f0 : NEG * f0;
            float f1 = a2.y + adn.y;
            f1 = f1 > 0.f ? f1 : NEG * f1;
            p0 = __expf(f0);
            p1 = __expf(f1);
            psum0 += p0;
            psum1 += p1;
        }
        int nt = (cnt + 3) >> 2;
#pragma unroll 8
        for (int t = 0; t < nt; t++) {
            int ej = t * 4 + g;
            int sj = __shfl(s, ej, 64);
            float pj0 = __shfl(p0, ej, 64);
            float pj1 = __shfl(p1, ej, 64);
            float pj = head1 ? pj1 : pj0;
            if (ej < cnt) {
                float4 raw = *reinterpret_cast<const float4*>(&hh[(size_t)sj * 128 + lc * 8]);
                const __half2* hp = reinterpret_cast<const __half2*>(&raw);
#pragma unroll
                for (int k = 0; k < 4; k++) {
                    float2 f = __half22float2(hp[k]);
                    acc[k].x += pj * f.x;
                    acc[k].y += pj * f.y;
                }
            }
        }
    }

#pragma unroll
    for (int m = 1; m < 64; m <<= 1) {
        psum0 += __shfl_xor(psum0, m, 64);
        psum1 += __shfl_xor(psum1, m, 64);
    }
    float inv0 = 1.f / (psum0 + pself0 + 1e-16f);
    float inv1 = 1.f / (psum1 + pself1 + 1e-16f);

#pragma unroll
    for (int m = 16; m < 64; m <<= 1) {
#pragma unroll
        for (int k = 0; k < 4; k++) {
            acc[k].x += __shfl_xor(acc[k].x, m, 64);
            acc[k].y += __shfl_xor(acc[k].y, m, 64);
        }
    }

    float inv = head1 ? inv1 : inv0;
    float pself = head1 ? pself1 : pself0;
    const __half2* sp = reinterpret_cast<const __half2*>(&sraw);
    float4 b0 = *reinterpret_cast<const float4*>(&bias[lc * 8]);
    float4 b1 = *reinterpret_cast<const float4*>(&bias[lc * 8 + 4]);
    float o[8];
#pragma unroll
    for (int k = 0; k < 4; k++) {
        float2 f = __half22float2(sp[k]);
        o[2 * k] = (acc[k].x + pself * f.x) * inv;
        o[2 * k + 1] = (acc[k].y + pself * f.y) * inv;
    }
    o[0] = fmaxf(o[0] + b0.x, 0.f);
    o[1] = fmaxf(o[1] + b0.y, 0.f);
    o[2] = fmaxf(o[2] + b0.z, 0.f);
    o[3] = fmaxf(o[3] + b0.w, 0.f);
    o[4] = fmaxf(o[4] + b1.x, 0.f);
    o[5] = fmaxf(o[5] + b1.y, 0.f);
    o[6] = fmaxf(o[6] + b1.z, 0.f);
    o[7] = fmaxf(o[7] + b1.w, 0.f);

    if (lane < 16) {
        uint4 cv;
        cv.x = pack2(o[0], o[1]);
        cv.y = pack2(o[2], o[3]);
        cv.z = pack2(o[4], o[5]);
        cv.w = pack2(o[6], o[7]);
        *reinterpret_cast<uint4*>(&outh[(size_t)node * 128 + lc * 8]) = cv;
    }
}

// ---------------- layer-2 GAT gather + fused final linear (R14/R16 layout) ----------------

__global__ __launch_bounds__(256) void k_gat1(const __half* __restrict__ hh,
                                              const float* __restrict__ asrc,
                                              const float* __restrict__ adst,
                                              const int* __restrict__ rowptr,
                                              const unsigned short* __restrict__ csr_src,
                                              const float* __restrict__ bias,
                                              const float* __restrict__ Wl,
                                              const float* __restrict__ bl,
                                              float* __restrict__ out, int n) {
    __shared__ float Wls[64 * 16];
    __shared__ float bls[16];
    __shared__ float hbuf[4][64];
    int tid = threadIdx.x;
    for (int i = tid; i < 64 * 16; i += 256) Wls[i] = Wl[i];
    if (tid < 16) bls[tid] = bl[tid];
    __syncthreads();

    int w = tid >> 6, lane = tid & 63;
    int node = blockIdx.x * 4 + w;
    if (node >= n) return;  // whole wave exits; only wave-local LDS below

    int beg = rowptr[node], end = rowptr[node + 1];
    float adn = adst[node];
    float e0 = asrc[node] + adn;
    e0 = e0 > 0.f ? e0 : NEG * e0;
    float pself = __expf(e0);

    int g = lane >> 3;  // edge group 0..7
    int lc = lane & 7;  // channel octet

    float4 sraw = *reinterpret_cast<const float4*>(&hh[(size_t)node * 64 + lc * 8]);

    float2 acc[4];
#pragma unroll
    for (int k = 0; k < 4; k++) acc[k] = make_float2(0.f, 0.f);
    float psum = 0.f;

    for (int base = beg; base < end; base += 64) {
        int i = base + lane;
        int cnt = min(64, end - base);
        float p = 0.f;
        int s = 0;
        if (i < end) {
            s = (int)csr_src[i];
            float e = asrc[s] + adn;
            e = e > 0.f ? e : NEG * e;
            p = __expf(e);
            psum += p;
        }
        int nt = (cnt + 7) >> 3;
#pragma unroll 8
        for (int t = 0; t < nt; t++) {
            int ej = t * 8 + g;
            int sj = __shfl(s, ej, 64);
            float pj = __shfl(p, ej, 64);
            if (ej < cnt) {
                float4 raw = *reinterpret_cast<const float4*>(&hh[(size_t)sj * 64 + lc * 8]);
                const __half2* hp = reinterpret_cast<const __half2*>(&raw);
#pragma unroll
                for (int k = 0; k < 4; k++) {
                    float2 f = __half22float2(hp[k]);
                    acc[k].x += pj * f.x;
                    acc[k].y += pj * f.y;
                }
            }
        }
    }

#pragma unroll
    for (int m = 1; m < 64; m <<= 1) psum += __shfl_xor(psum, m, 64);
    float inv = 1.f / (psum + pself + 1e-16f);

#pragma unroll
    for (int m = 8; m < 64; m <<= 1) {
#pragma unroll
        for (int k = 0; k < 4; k++) {
            acc[k].x += __shfl_xor(acc[k].x, m, 64);
            acc[k].y += __shfl_xor(acc[k].y, m, 64);
        }
    }

    const __half2* sp = reinterpret_cast<const __half2*>(&sraw);
    float4 b0 = *reinterpret_cast<const float4*>(&bias[lc * 8]);
    float4 b1 = *reinterpret_cast<const float4*>(&bias[lc * 8 + 4]);
    float o[8];
#pragma unroll
    for (int k = 0; k < 4; k++) {
        float2 f = __half22float2(sp[k]);
        o[2 * k] = (acc[k].x + pself * f.x) * inv;
        o[2 * k + 1] = (acc[k].y + pself * f.y) * inv;
    }
    o[0] = fmaxf(o[0] + b0.x, 0.f);
    o[1] = fmaxf(o[1] + b0.y, 0.f);
    o[2] = fmaxf(o[2] + b0.z, 0.f);
    o[3] = fmaxf(o[3] + b0.w, 0.f);
    o[4] = fmaxf(o[4] + b1.x, 0.f);
    o[5] = fmaxf(o[5] + b1.y, 0.f);
    o[6] = fmaxf(o[6] + b1.z, 0.f);
    o[7] = fmaxf(o[7] + b1.w, 0.f);

    if (lane < 8) {
        float* hp = &hbuf[w][lc * 8];
        *reinterpret_cast<float4*>(hp) = make_float4(o[0], o[1], o[2], o[3]);
        *reinterpret_cast<float4*>(hp + 4) = make_float4(o[4], o[5], o[6], o[7]);
    }
    __builtin_amdgcn_wave_barrier();  // wave-local LDS RAW: HW in-order, fence compiler

    int col = lane & 15, q = lane >> 4;
    float a = 0.f;
#pragma unroll
    for (int k = 0; k < 16; k++) {
        int kk = q * 16 + k;
        a += hbuf[w][kk] * Wls[kk * 16 + col];
    }
    a += __shfl_xor(a, 16, 64);
    a += __shfl_xor(a, 32, 64);
    if (lane < 16) out[(size_t)node * 16 + col] = a + bls[col];
}

// ---------------- launch ----------------

extern "C" void kernel_launch(void* const* d_in, const int* in_sizes, int n_in,
                              void* d_out, int out_size, void* d_ws, size_t ws_size,
                              hipStream_t stream) {
    const float* x      = (const float*)d_in[0];
    const int*   ei     = (const int*)d_in[1];
    const float* W1     = (const float*)d_in[2];
    const float* a_src1 = (const float*)d_in[3];
    const float* a_dst1 = (const float*)d_in[4];
    const float* b1     = (const float*)d_in[5];
    const float* W2     = (const float*)d_in[6];
    const float* a_src2 = (const float*)d_in[7];
    const float* a_dst2 = (const float*)d_in[8];
    const float* b2     = (const float*)d_in[9];
    const float* Wl     = (const float*)d_in[10];
    const float* bl     = (const float*)d_in[11];
    float* out = (float*)d_out;

    int n = in_sizes[0] / 128;
    int E = in_sizes[1] / 2;
    const int* src = ei;
    const int* dst = ei + E;
    int NRg = (n + RW - 1) >> RSH;  // 98 for n=50000 (<=128)

    char* w = (char*)d_ws;
    size_t off = 0;
    auto alloc = [&](size_t bytes) {
        void* p = w + off;
        off = (off + bytes + 255) & ~(size_t)255;
        return p;
    };
    int*            rcur   = (int*)alloc(128 * 4);
    unsigned int*   part   = (unsigned int*)alloc((size_t)NRg * RCAP * 4);
    int*            rowptr = (int*)alloc((size_t)(n + 1) * 4);
    unsigned short* csr    = (unsigned short*)alloc((size_t)E * 2);
    __half*         wt1    = (__half*)alloc(128 * 128 * 2);
    __half*         wt2    = (__half*)alloc(64 * 128 * 2);
    __half*         h1h    = (__half*)alloc((size_t)n * 128 * 2);
    float*          as1    = (float*)alloc((size_t)n * 2 * 4);
    float*          ad1    = (float*)alloc((size_t)n * 2 * 4);
    __half*         hmh    = (__half*)alloc((size_t)n * 128 * 2);
    __half*         h2h    = (__half*)alloc((size_t)n * 64 * 2);
    float*          as2    = (float*)alloc((size_t)n * 4);
    float*          ad2    = (float*)alloc((size_t)n * 4);

    hipMemsetAsync(rcur, 0, 128 * 4, stream);

    int gblocks = (n + 31) / 32;      // 1563
    int bblocks = (E + 2047) / 2048;  // 782
    int half = gblocks > bblocks ? gblocks : bblocks;

    k_prep<<<6, 256, 0, stream>>>(W1, W2, wt1, wt2);

    // layer 1 (heads=2): even blocks MFMA GEMM tile, odd blocks edge partition
    k_gemm<128, 128, 2, true, false><<<2 * half, 256, 0, stream>>>(
        x, wt1, a_src1, a_dst1, h1h, as1, ad1, n, src, dst, E, NRg, gblocks, bblocks, rcur, part);
    k_build<<<NRg, 512, 0, stream>>>(part, rcur, n, csr, rowptr);
    k_gat2<<<(n + 3) / 4, 256, 0, stream>>>(h1h, as1, ad1, rowptr, csr, b1, hmh, n);

    // layer 2 (heads=1), final linear fused into the gather
    k_gemm<128, 64, 1, false, true><<<gblocks, 256, 0, stream>>>(
        hmh, wt2, a_src2, a_dst2, h2h, as2, ad2, n, nullptr, nullptr, 0, 0, 0, 0, nullptr, nullptr);
    k_gat1<<<(n + 3) / 4, 256, 0, stream>>>(h2h, as2, ad2, rowptr, csr, b2, Wl, bl, out, n);
}

// Round 18
// 187.044 us; speedup vs baseline: 1.0320x; 1.0320x over previous
//
#include <hip/hip_runtime.h>
#include <hip/hip_fp16.h>

#define NEG 0.2f
#define RW 512      // nodes per region
#define RSH 9       // log2(RW)
#define RCAP 18432  // region edge capacity: mean 16384, sigma ~127 -> +16 sigma

typedef _Float16 hfx2 __attribute__((ext_vector_type(2)));

__device__ __forceinline__ float fdot2u(unsigned int a, unsigned int b, float c) {
#if __has_builtin(__builtin_amdgcn_fdot2)
    union { unsigned int u; hfx2 h; } ua, ub;
    ua.u = a; ub.u = b;
    return __builtin_amdgcn_fdot2(ua.h, ub.h, c, false);
#else
    union { unsigned int u; __half2 h; } ua, ub;
    ua.u = a; ub.u = b;
    float2 fa = __half22float2(ua.h), fb = __half22float2(ub.h);
    return c + fa.x * fb.x + fa.y * fb.y;
#endif
}

__device__ __forceinline__ unsigned int pack2(float lo, float hi) {
    union { __half2 h; unsigned int u; } cv;
    cv.h = __floats2half2_rn(lo, hi);
    return cv.u;
}

// ---------------- GEMM (fp16 LDS + dot2) + fused scores (+ co-scheduled partition) ----------------
// Yh[n,M] (fp16) = X[n,K] @ W[K,M]; asrc/adst[n,H] = rowdots (fp32 accumulators).
// 32-row tiles: short per-block critical path, LDS 17.8 KB -> deep block queue
// per CU (tail-fill pipelining). PART: EVEN blocks = GEMM tile, ODD = edge
// partition chunk (LDS histograms, ONE global atomic per block-region).
// k8 loop pinned unroll 1 (R9: full unroll spilled to scratch).

template <int K, int M, int H, bool PART, bool XHALF>
__global__ __launch_bounds__(256) void k_gemm(const void* __restrict__ Xv,
                                              const float* __restrict__ W,
                                              const float* __restrict__ a_src,
                                              const float* __restrict__ a_dst,
                                              __half* __restrict__ Yh,
                                              float* __restrict__ asrc,
                                              float* __restrict__ adst, int n,
                                              const int* __restrict__ esrc,
                                              const int* __restrict__ edst, int E,
                                              int NRg, int gemmCount, int partCount,
                                              int* rcur, unsigned int* part) {
    constexpr int KH = 32;
    constexpr int NQ = M / 64;   // col-quads per thread: 2 (M=128) or 1 (M=64)
    constexpr int ROWS = 32;
    constexpr int RPT = ROWS / 16;  // rows per thread = 2
    __shared__ __half Xs[ROWS][K + 8];        // 272B rows (K=128): 16B-aligned
    __shared__ unsigned int Wp[KH / 2][M];    // pair-packed: (W[2kp][m], W[2kp+1][m])
    int tid = threadIdx.x;
    int bix = PART ? (blockIdx.x >> 1) : blockIdx.x;

    if (PART && (blockIdx.x & 1)) {
        // ---------- partition-only block ----------
        if (bix >= partCount) return;
        __shared__ int ph[128];
        __shared__ int pb[128];
        int i0 = (bix * 256 + tid) * 8;
        int ds[8], ss[8];
        if (i0 + 7 < E) {
            int4 a = *reinterpret_cast<const int4*>(&edst[i0]);
            int4 b = *reinterpret_cast<const int4*>(&edst[i0 + 4]);
            ds[0] = a.x; ds[1] = a.y; ds[2] = a.z; ds[3] = a.w;
            ds[4] = b.x; ds[5] = b.y; ds[6] = b.z; ds[7] = b.w;
            int4 c = *reinterpret_cast<const int4*>(&esrc[i0]);
            int4 d = *reinterpret_cast<const int4*>(&esrc[i0 + 4]);
            ss[0] = c.x; ss[1] = c.y; ss[2] = c.z; ss[3] = c.w;
            ss[4] = d.x; ss[5] = d.y; ss[6] = d.z; ss[7] = d.w;
        } else {
#pragma unroll
            for (int j = 0; j < 8; j++) {
                ds[j] = (i0 + j < E) ? edst[i0 + j] : 0;
                ss[j] = (i0 + j < E) ? esrc[i0 + j] : 0;
            }
        }
        if (tid < NRg) ph[tid] = 0;
        __syncthreads();
#pragma unroll
        for (int j = 0; j < 8; j++)
            if (i0 + j < E) atomicAdd(&ph[ds[j] >> RSH], 1);
        __syncthreads();
        if (tid < NRg) {
            int c = ph[tid];
            pb[tid] = c ? atomicAdd(&rcur[tid], c) : 0;  // coarse reserve
            ph[tid] = 0;
        }
        __syncthreads();
#pragma unroll
        for (int j = 0; j < 8; j++) {
            if (i0 + j < E) {
                int r = ds[j] >> RSH;
                int rk = atomicAdd(&ph[r], 1) + pb[r];
                if (rk < RCAP)
                    part[(size_t)r * RCAP + rk] =
                        ((unsigned int)(ds[j] & (RW - 1)) << 16) | (unsigned int)(ss[j] & 0xFFFF);
            }
        }
        return;
    }
    if (PART && bix >= gemmCount) return;
    int row0 = bix * ROWS;

    // ---- stage X tile (ROWS rows, full K) as fp16 ----
    if (XHALF) {
        const __half* Xh = (const __half*)Xv;
        for (int idx = tid; idx < ROWS * (K / 8); idx += 256) {
            int r = idx / (K / 8), c8 = idx % (K / 8);
            int gr = row0 + r;
            uint4 v = make_uint4(0u, 0u, 0u, 0u);
            if (gr < n) v = *reinterpret_cast<const uint4*>(&Xh[(size_t)gr * K + c8 * 8]);
            *reinterpret_cast<uint4*>(&Xs[r][c8 * 8]) = v;
        }
    } else {
        const float* X = (const float*)Xv;
        for (int idx = tid; idx < ROWS * (K / 8); idx += 256) {
            int r = idx / (K / 8), c8 = idx % (K / 8);
            int gr = row0 + r;
            uint4 pk = make_uint4(0u, 0u, 0u, 0u);
            if (gr < n) {
                float4 a = *reinterpret_cast<const float4*>(&X[(size_t)gr * K + c8 * 8]);
                float4 b = *reinterpret_cast<const float4*>(&X[(size_t)gr * K + c8 * 8 + 4]);
                pk.x = pack2(a.x, a.y);
                pk.y = pack2(a.z, a.w);
                pk.z = pack2(b.x, b.y);
                pk.w = pack2(b.z, b.w);
            }
            *reinterpret_cast<uint4*>(&Xs[r][c8 * 8]) = pk;
        }
    }

    int rg = tid >> 4;  // 0..15 -> rows rg*RPT..rg*RPT+RPT-1
    int cq = tid & 15;  // quads cq + 16*qi

    float4 acc[RPT][NQ];
#pragma unroll
    for (int j = 0; j < RPT; j++)
#pragma unroll
        for (int qi = 0; qi < NQ; qi++) acc[j][qi] = make_float4(0.f, 0.f, 0.f, 0.f);

    for (int kh = 0; kh < K; kh += KH) {
        __syncthreads();
        // stage Wp: pair-pack rows kh..kh+KH-1
        for (int c = tid; c < (KH / 2) * (M / 4); c += 256) {
            int kp = c / (M / 4), m4 = (c % (M / 4)) * 4;
            float4 a = *reinterpret_cast<const float4*>(&W[(size_t)(kh + 2 * kp) * M + m4]);
            float4 b = *reinterpret_cast<const float4*>(&W[(size_t)(kh + 2 * kp + 1) * M + m4]);
            uint4 pk;
            pk.x = pack2(a.x, b.x);
            pk.y = pack2(a.y, b.y);
            pk.z = pack2(a.z, b.z);
            pk.w = pack2(a.w, b.w);
            *reinterpret_cast<uint4*>(&Wp[kp][m4]) = pk;
        }
        __syncthreads();
#pragma unroll 1
        for (int k8 = 0; k8 < KH; k8 += 8) {
            uint4 x0 = *reinterpret_cast<const uint4*>(&Xs[rg * RPT + 0][kh + k8]);
            uint4 x1 = *reinterpret_cast<const uint4*>(&Xs[rg * RPT + 1][kh + k8]);
            unsigned int xa0[4] = {x0.x, x0.y, x0.z, x0.w};
            unsigned int xa1[4] = {x1.x, x1.y, x1.z, x1.w};
            int kp0 = k8 >> 1;
#pragma unroll
            for (int p = 0; p < 4; p++) {
#pragma unroll
                for (int qi = 0; qi < NQ; qi++) {
                    uint4 wv =
                        *reinterpret_cast<const uint4*>(&Wp[kp0 + p][(cq + 16 * qi) * 4]);
                    acc[0][qi].x = fdot2u(xa0[p], wv.x, acc[0][qi].x);
                    acc[0][qi].y = fdot2u(xa0[p], wv.y, acc[0][qi].y);
                    acc[0][qi].z = fdot2u(xa0[p], wv.z, acc[0][qi].z);
                    acc[0][qi].w = fdot2u(xa0[p], wv.w, acc[0][qi].w);
                    acc[1][qi].x = fdot2u(xa1[p], wv.x, acc[1][qi].x);
                    acc[1][qi].y = fdot2u(xa1[p], wv.y, acc[1][qi].y);
                    acc[1][qi].z = fdot2u(xa1[p], wv.z, acc[1][qi].z);
                    acc[1][qi].w = fdot2u(xa1[p], wv.w, acc[1][qi].w);
                }
            }
        }
    }

    // ---- fp16 store ----
#pragma unroll
    for (int j = 0; j < RPT; j++) {
        int gr = row0 + rg * RPT + j;
        if (gr < n) {
#pragma unroll
            for (int qi = 0; qi < NQ; qi++) {
                uint2 cv;
                cv.x = pack2(acc[j][qi].x, acc[j][qi].y);
                cv.y = pack2(acc[j][qi].z, acc[j][qi].w);
                *reinterpret_cast<uint2*>(&Yh[(size_t)gr * M + (cq + 16 * qi) * 4]) = cv;
            }
        }
    }

    // ---- fused score dots (fp32 accumulators) ----
    float4 av0 = *reinterpret_cast<const float4*>(&a_src[cq * 4]);
    float4 dv0 = *reinterpret_cast<const float4*>(&a_dst[cq * 4]);
    float4 av1 = av0, dv1 = dv0;
    if (NQ == 2) {
        av1 = *reinterpret_cast<const float4*>(&a_src[(cq + 16) * 4]);
        dv1 = *reinterpret_cast<const float4*>(&a_dst[(cq + 16) * 4]);
    }
#pragma unroll
    for (int j = 0; j < RPT; j++) {
        float s0 = acc[j][0].x * av0.x + acc[j][0].y * av0.y + acc[j][0].z * av0.z +
                   acc[j][0].w * av0.w;
        float d0 = acc[j][0].x * dv0.x + acc[j][0].y * dv0.y + acc[j][0].z * dv0.z +
                   acc[j][0].w * dv0.w;
        float s1 = 0.f, d1 = 0.f;
        if (NQ == 2) {
            s1 = acc[j][1].x * av1.x + acc[j][1].y * av1.y + acc[j][1].z * av1.z +
                 acc[j][1].w * av1.w;
            d1 = acc[j][1].x * dv1.x + acc[j][1].y * dv1.y + acc[j][1].z * dv1.z +
                 acc[j][1].w * dv1.w;
        }
#pragma unroll
        for (int m = 1; m < 16; m <<= 1) {
            s0 += __shfl_xor(s0, m, 64);
            d0 += __shfl_xor(d0, m, 64);
            if (NQ == 2) {
                s1 += __shfl_xor(s1, m, 64);
                d1 += __shfl_xor(d1, m, 64);
            }
        }
        int gr = row0 + rg * RPT + j;
        if (cq == 0 && gr < n) {
            if (H == 2) {
                *reinterpret_cast<float2*>(&asrc[gr * 2]) = make_float2(s0, s1);
                *reinterpret_cast<float2*>(&adst[gr * 2]) = make_float2(d0, d1);
            } else {
                asrc[gr] = s0;
                adst[gr] = d0;
            }
        }
    }
}

// ---------------- k_build: per-region count(LDS) + scan(LDS) -> rowptr + compact csr ----------------

__global__ __launch_bounds__(512) void k_build(const unsigned int* __restrict__ part,
                                               const int* __restrict__ rcur, int n,
                                               unsigned short* __restrict__ csr,
                                               int* __restrict__ rowptr) {
    __shared__ int hist[RW];
    __shared__ int wsum[8];
    __shared__ int rbase_s;
    int r = blockIdx.x;
    int tid = threadIdx.x, lane = tid & 63, wid = tid >> 6;
    int cnt = min(rcur[r], RCAP);
    if (tid == 0) {
        int b = 0;
        for (int j = 0; j < r; j++) b += min(rcur[j], RCAP);
        rbase_s = b;
    }
    hist[tid] = 0;
    __syncthreads();
    int rbase = rbase_s;
    const unsigned int* pr = part + (size_t)r * RCAP;

    for (int i = tid; i < cnt; i += 512) atomicAdd(&hist[pr[i] >> 16], 1);
    __syncthreads();

    int v = hist[tid];
    int incl = v;
#pragma unroll
    for (int m = 1; m < 64; m <<= 1) {
        int t = __shfl_up(incl, m, 64);
        if (lane >= m) incl += t;
    }
    if (lane == 63) wsum[wid] = incl;
    __syncthreads();
    if (wid == 0) {
        int s = (lane < 8) ? wsum[lane] : 0;
#pragma unroll
        for (int m = 1; m < 8; m <<= 1) {
            int t = __shfl_up(s, m, 64);
            if (lane >= m) s += t;
        }
        if (lane < 8) wsum[lane] = s;
    }
    __syncthreads();
    int excl = (incl - v) + (wid > 0 ? wsum[wid - 1] : 0);
    __syncthreads();
    hist[tid] = excl;  // becomes running cursor
    int g = r * RW + tid;
    if (g < n) rowptr[g] = rbase + excl;
    if (r == gridDim.x - 1 && tid == 0) rowptr[n] = rbase + cnt;
    __syncthreads();

    for (int i = tid; i < cnt; i += 512) {
        unsigned int e = pr[i];
        int rk = atomicAdd(&hist[e >> 16], 1);
        csr[rbase + rk] = (unsigned short)(e & 0xFFFF);
    }
}

// ---------------- layer-1 GAT gather (both heads), fp16 in/out ----------------
// One wave per node; 16-lane groups, 4 edges in flight; per-edge scalar work
// shared across both heads. Unnormalized-p aggregation; max-subtract skipped
// (scores O(1), shift-invariant).

__global__ __launch_bounds__(256) void k_gat2(const __half* __restrict__ hh,
                                              const float* __restrict__ asrc,
                                              const float* __restrict__ adst,
                                              const int* __restrict__ rowptr,
                                              const unsigned short* __restrict__ csr_src,
                                              const float* __restrict__ bias,
                                              __half* __restrict__ outh, int n) {
    int node = blockIdx.x * 4 + (threadIdx.x >> 6);
    int lane = threadIdx.x & 63;
    if (node >= n) return;

    int beg = rowptr[node], end = rowptr[node + 1];
    float2 adn = *reinterpret_cast<const float2*>(&adst[node * 2]);
    float2 asn = *reinterpret_cast<const float2*>(&asrc[node * 2]);
    float e0 = asn.x + adn.x;
    e0 = e0 > 0.f ? e0 : NEG * e0;
    float e1 = asn.y + adn.y;
    e1 = e1 > 0.f ? e1 : NEG * e1;
    float pself0 = __expf(e0), pself1 = __expf(e1);

    int g = lane >> 4;   // edge group 0..3
    int lc = lane & 15;  // channel octet
    bool head1 = lc >= 8;

    float4 sraw = *reinterpret_cast<const float4*>(&hh[(size_t)node * 128 + lc * 8]);

    float2 acc[4];
#pragma unroll
    for (int k = 0; k < 4; k++) acc[k] = make_float2(0.f, 0.f);
    float psum0 = 0.f, psum1 = 0.f;

    for (int base = beg; base < end; base += 64) {
        int i = base + lane;
        int cnt = min(64, end - base);
        float p0 = 0.f, p1 = 0.f;
        int s = 0;
        if (i < end) {
            s = (int)csr_src[i];
            float2 a2 = *reinterpret_cast<const float2*>(&asrc[s * 2]);
            float f0 = a2.x + adn.x;
            f0 = f0 > 0.f ? f0 : NEG * f0;
            float f1 = a2.y + adn.y;
            f1 = f1 > 0.f ? f1 : NEG * f1;
            p0 = __expf(f0);
            p1 = __expf(f1);
            psum0 += p0;
            psum1 += p1;
        }
        int nt = (cnt + 3) >> 2;
#pragma unroll 8
        for (int t = 0; t < nt; t++) {
            int ej = t * 4 + g;
            int sj = __shfl(s, ej, 64);
            float pj0 = __shfl(p0, ej, 64);
            float pj1 = __shfl(p1, ej, 64);
            float pj = head1 ? pj1 : pj0;
            if (ej < cnt) {
                float4 raw = *reinterpret_cast<const float4*>(&hh[(size_t)sj * 128 + lc * 8]);
                const __half2* hp = reinterpret_cast<const __half2*>(&raw);
#pragma unroll
                for (int k = 0; k < 4; k++) {
                    float2 f = __half22float2(hp[k]);
                    acc[k].x += pj * f.x;
                    acc[k].y += pj * f.y;
                }
            }
        }
    }

#pragma unroll
    for (int m = 1; m < 64; m <<= 1) {
        psum0 += __shfl_xor(psum0, m, 64);
        psum1 += __shfl_xor(psum1, m, 64);
    }
    float inv0 = 1.f / (psum0 + pself0 + 1e-16f);
    float inv1 = 1.f / (psum1 + pself1 + 1e-16f);

#pragma unroll
    for (int m = 16; m < 64; m <<= 1) {
#pragma unroll
        for (int k = 0; k < 4; k++) {
            acc[k].x += __shfl_xor(acc[k].x, m, 64);
            acc[k].y += __shfl_xor(acc[k].y, m, 64);
        }
    }

    float inv = head1 ? inv1 : inv0;
    float pself = head1 ? pself1 : pself0;
    const __half2* sp = reinterpret_cast<const __half2*>(&sraw);
    float4 b0 = *reinterpret_cast<const float4*>(&bias[lc * 8]);
    float4 b1 = *reinterpret_cast<const float4*>(&bias[lc * 8 + 4]);
    float o[8];
#pragma unroll
    for (int k = 0; k < 4; k++) {
        float2 f = __half22float2(sp[k]);
        o[2 * k] = (acc[k].x + pself * f.x) * inv;
        o[2 * k + 1] = (acc[k].y + pself * f.y) * inv;
    }
    o[0] = fmaxf(o[0] + b0.x, 0.f);
    o[1] = fmaxf(o[1] + b0.y, 0.f);
    o[2] = fmaxf(o[2] + b0.z, 0.f);
    o[3] = fmaxf(o[3] + b0.w, 0.f);
    o[4] = fmaxf(o[4] + b1.x, 0.f);
    o[5] = fmaxf(o[5] + b1.y, 0.f);
    o[6] = fmaxf(o[6] + b1.z, 0.f);
    o[7] = fmaxf(o[7] + b1.w, 0.f);

    if (lane < 16) {
        uint4 cv;
        cv.x = pack2(o[0], o[1]);
        cv.y = pack2(o[2], o[3]);
        cv.z = pack2(o[4], o[5]);
        cv.w = pack2(o[6], o[7]);
        *reinterpret_cast<uint4*>(&outh[(size_t)node * 128 + lc * 8]) = cv;
    }
}

// ---------------- layer-2 GAT gather + fused final linear ----------------
// One wave per node; 8-lane groups (lane owns 8 ch), 8 edges in flight.

__global__ __launch_bounds__(256) void k_gat1(const __half* __restrict__ hh,
                                              const float* __restrict__ asrc,
                                              const float* __restrict__ adst,
                                              const int* __restrict__ rowptr,
                                              const unsigned short* __restrict__ csr_src,
                                              const float* __restrict__ bias,
                                              const float* __restrict__ Wl,
                                              const float* __restrict__ bl,
                                              float* __restrict__ out, int n) {
    __shared__ float Wls[64 * 16];
    __shared__ float bls[16];
    __shared__ float hbuf[4][64];
    int tid = threadIdx.x;
    for (int i = tid; i < 64 * 16; i += 256) Wls[i] = Wl[i];
    if (tid < 16) bls[tid] = bl[tid];
    __syncthreads();

    int w = tid >> 6, lane = tid & 63;
    int node = blockIdx.x * 4 + w;
    if (node >= n) return;  // whole wave exits; only wave-local LDS below

    int beg = rowptr[node], end = rowptr[node + 1];
    float adn = adst[node];
    float e0 = asrc[node] + adn;
    e0 = e0 > 0.f ? e0 : NEG * e0;
    float pself = __expf(e0);

    int g = lane >> 3;  // edge group 0..7
    int lc = lane & 7;  // channel octet

    float4 sraw = *reinterpret_cast<const float4*>(&hh[(size_t)node * 64 + lc * 8]);

    float2 acc[4];
#pragma unroll
    for (int k = 0; k < 4; k++) acc[k] = make_float2(0.f, 0.f);
    float psum = 0.f;

    for (int base = beg; base < end; base += 64) {
        int i = base + lane;
        int cnt = min(64, end - base);
        float p = 0.f;
        int s = 0;
        if (i < end) {
            s = (int)csr_src[i];
            float e = asrc[s] + adn;
            e = e > 0.f ? e : NEG * e;
            p = __expf(e);
            psum += p;
        }
        int nt = (cnt + 7) >> 3;
#pragma unroll 8
        for (int t = 0; t < nt; t++) {
            int ej = t * 8 + g;
            int sj = __shfl(s, ej, 64);
            float pj = __shfl(p, ej, 64);
            if (ej < cnt) {
                float4 raw = *reinterpret_cast<const float4*>(&hh[(size_t)sj * 64 + lc * 8]);
                const __half2* hp = reinterpret_cast<const __half2*>(&raw);
#pragma unroll
                for (int k = 0; k < 4; k++) {
                    float2 f = __half22float2(hp[k]);
                    acc[k].x += pj * f.x;
                    acc[k].y += pj * f.y;
                }
            }
        }
    }

#pragma unroll
    for (int m = 1; m < 64; m <<= 1) psum += __shfl_xor(psum, m, 64);
    float inv = 1.f / (psum + pself + 1e-16f);

#pragma unroll
    for (int m = 8; m < 64; m <<= 1) {
#pragma unroll
        for (int k = 0; k < 4; k++) {
            acc[k].x += __shfl_xor(acc[k].x, m, 64);
            acc[k].y += __shfl_xor(acc[k].y, m, 64);
        }
    }

    const __half2* sp = reinterpret_cast<const __half2*>(&sraw);
    float4 b0 = *reinterpret_cast<const float4*>(&bias[lc * 8]);
    float4 b1 = *reinterpret_cast<const float4*>(&bias[lc * 8 + 4]);
    float o[8];
#pragma unroll
    for (int k = 0; k < 4; k++) {
        float2 f = __half22float2(sp[k]);
        o[2 * k] = (acc[k].x + pself * f.x) * inv;
        o[2 * k + 1] = (acc[k].y + pself * f.y) * inv;
    }
    o[0] = fmaxf(o[0] + b0.x, 0.f);
    o[1] = fmaxf(o[1] + b0.y, 0.f);
    o[2] = fmaxf(o[2] + b0.z, 0.f);
    o[3] = fmaxf(o[3] + b0.w, 0.f);
    o[4] = fmaxf(o[4] + b1.x, 0.f);
    o[5] = fmaxf(o[5] + b1.y, 0.f);
    o[6] = fmaxf(o[6] + b1.z, 0.f);
    o[7] = fmaxf(o[7] + b1.w, 0.f);

    if (lane < 8) {
        float* hp = &hbuf[w][lc * 8];
        *reinterpret_cast<float4*>(hp) = make_float4(o[0], o[1], o[2], o[3]);
        *reinterpret_cast<float4*>(hp + 4) = make_float4(o[4], o[5], o[6], o[7]);
    }
    __builtin_amdgcn_wave_barrier();  // wave-local LDS RAW: HW in-order, fence compiler

    int col = lane & 15, q = lane >> 4;
    float a = 0.f;
#pragma unroll
    for (int k = 0; k < 16; k++) {
        int kk = q * 16 + k;
        a += hbuf[w][kk] * Wls[kk * 16 + col];
    }
    a += __shfl_xor(a, 16, 64);
    a += __shfl_xor(a, 32, 64);
    if (lane < 16) out[(size_t)node * 16 + col] = a + bls[col];
}

// ---------------- launch ----------------

extern "C" void kernel_launch(void* const* d_in, const int* in_sizes, int n_in,
                              void* d_out, int out_size, void* d_ws, size_t ws_size,
                              hipStream_t stream) {
    const float* x      = (const float*)d_in[0];
    const int*   ei     = (const int*)d_in[1];
    const float* W1     = (const float*)d_in[2];
    const float* a_src1 = (const float*)d_in[3];
    const float* a_dst1 = (const float*)d_in[4];
    const float* b1     = (const float*)d_in[5];
    const float* W2     = (const float*)d_in[6];
    const float* a_src2 = (const float*)d_in[7];
    const float* a_dst2 = (const float*)d_in[8];
    const float* b2     = (const float*)d_in[9];
    const float* Wl     = (const float*)d_in[10];
    const float* bl     = (const float*)d_in[11];
    float* out = (float*)d_out;

    int n = in_sizes[0] / 128;
    int E = in_sizes[1] / 2;
    const int* src = ei;
    const int* dst = ei + E;
    int NRg = (n + RW - 1) >> RSH;  // 98 for n=50000 (<=128)

    char* w = (char*)d_ws;
    size_t off = 0;
    auto alloc = [&](size_t bytes) {
        void* p = w + off;
        off = (off + bytes + 255) & ~(size_t)255;
        return p;
    };
    int*            rcur   = (int*)alloc(128 * 4);
    unsigned int*   part   = (unsigned int*)alloc((size_t)NRg * RCAP * 4);
    int*            rowptr = (int*)alloc((size_t)(n + 1) * 4);
    unsigned short* csr    = (unsigned short*)alloc((size_t)E * 2);
    __half*         h1h    = (__half*)alloc((size_t)n * 128 * 2);
    float*          as1    = (float*)alloc((size_t)n * 2 * 4);
    float*          ad1    = (float*)alloc((size_t)n * 2 * 4);
    __half*         hmh    = (__half*)alloc((size_t)n * 128 * 2);
    __half*         h2h    = (__half*)alloc((size_t)n * 64 * 2);
    float*          as2    = (float*)alloc((size_t)n * 4);
    float*          ad2    = (float*)alloc((size_t)n * 4);

    hipMemsetAsync(rcur, 0, 128 * 4, stream);

    int gblocks = (n + 31) / 32;      // 1563 (32-row tiles)
    int bblocks = (E + 2047) / 2048;  // 782
    int half = gblocks > bblocks ? gblocks : bblocks;

    // layer 1 (heads=2): even blocks GEMM tile, odd blocks edge partition
    k_gemm<128, 128, 2, true, false><<<2 * half, 256, 0, stream>>>(
        x, W1, a_src1, a_dst1, h1h, as1, ad1, n, src, dst, E, NRg, gblocks, bblocks, rcur, part);
    k_build<<<NRg, 512, 0, stream>>>(part, rcur, n, csr, rowptr);
    k_gat2<<<(n + 3) / 4, 256, 0, stream>>>(h1h, as1, ad1, rowptr, csr, b1, hmh, n);

    // layer 2 (heads=1), final linear fused into the gather
    k_gemm<128, 64, 1, false, true><<<gblocks, 256, 0, stream>>>(
        hmh, W2, a_src2, a_dst2, h2h, as2, ad2, n, nullptr, nullptr, 0, 0, 0, 0, nullptr, nullptr);
    k_gat1<<<(n + 3) / 4, 256, 0, stream>>>(h2h, as2, ad2, rowptr, csr, b2, Wl, bl, out, n);
}